// Round 6
// baseline (9.738 us; speedup 1.0000x reference)
//
#include <hip/hip_runtime.h>
#include <math.h>

// One block per output column o = blockIdx.x (256 blocks = 1/CU).
// out[b,o] = W(b,o)*se_b + W(b,o+256)*so_b + bias(b,o), where
//   W(b,m)  = relu(PE1[m] + x[b,m]*w1[32]) @ w2 + b2
//   PE1[m]  = pe(m)@w1[0:16] + pe(o)@w1[16:32] + b1        (batch-independent)
//   bias    = relu(PEO[o] + out*bw1[16]) @ bw2 + bb2, PEO[o] = pe(o)@bw1[0:16] + bb1
//   se/so   = sums of even/odd-indexed x[b,:]
// Waves 0-2 build the 3 PE rows (coalesced global reads); thread t=(bt=t>>3, s8=t&7)
// does per-batch work with butterfly shuffles; single __syncthreads.
// Parity loads are lane-contiguous: chunk = s8 + 8q -> 128B runs, not 64-line scatter.

// c_rcs[q] = 10000^(-q/8) / (2*pi)   (v_sin/v_cos take revolutions)
__device__ __constant__ float c_rcs[8] = {
    0.15915494309189535f,   0.05032921210448703f,
    0.015915494309189535f,  0.005032921210448703f,
    0.0015915494309189535f, 0.0005032921210448703f,
    0.00015915494309189535f, 5.0329212104487035e-05f };

__device__ inline void pe_trig(int idx, float* s, float* c) {
    #pragma unroll
    for (int q = 0; q < 8; ++q) {
        float r = (float)idx * c_rcs[q];
        r -= floorf(r);
        s[q] = __builtin_amdgcn_sinf(r);
        c[q] = __builtin_amdgcn_cosf(r);
    }
}

__global__ __launch_bounds__(256) void vnn_fused(
    const float* __restrict__ x,
    const float* __restrict__ w1,  const float* __restrict__ b1,
    const float* __restrict__ w2,  const float* __restrict__ b2,
    const float* __restrict__ bw1, const float* __restrict__ bb1,
    const float* __restrict__ bw2, const float* __restrict__ bb2,
    float* __restrict__ out)
{
    __shared__ __attribute__((aligned(16))) float PE1s[2][64];
    __shared__ __attribute__((aligned(16))) float PEOs[64];
    __shared__ __attribute__((aligned(16))) float w1cS[64], w2S[64], bwcS[64], bw2S[64];
    __shared__ float ses[32], sos[32];

    const int t  = threadIdx.x;
    const int j  = blockIdx.x;      // output column o = j
    const int l  = t & 63;
    const int w  = t >> 6;          // wave id
    const int bt = t >> 3;          // batch
    const int s8 = t & 7;           // h-slice / chunk-lane id

    // uniform scalars (compiler emits s_load; no LDS round-trip)
    const float b2s_  = b2[0];
    const float bb2s_ = bb2[0];

    // per-batch x entries used by the weight MLP (issued early)
    const float xv0 = x[bt * 512 + j];
    const float xv1 = x[bt * 512 + j + 256];

    // ---- parity sums of x[bt,:]: lane-contiguous chunks (coalesced 128B runs) ----
    {
        float pesum = 0.f, posum = 0.f;
        const float4* xp = (const float4*)(x + bt * 512);
        #pragma unroll
        for (int q = 0; q < 16; ++q) {
            const float4 v = xp[s8 + 8 * q];   // lanes s8=0..7 contiguous
            pesum += v.x + v.z;
            posum += v.y + v.w;
        }
        #pragma unroll
        for (int mask = 1; mask <= 4; mask <<= 1) {
            pesum += __shfl_xor(pesum, mask);
            posum += __shfl_xor(posum, mask);
        }
        if (s8 == 0) { ses[bt] = pesum; sos[bt] = posum; }
    }

    // ---- build the 3 PE rows + stage small vectors (one wave each) ----
    if (w == 0) {
        float s[8], c[8];
        pe_trig(j, s, c);                  // pe(m=j) and pe(o=j) coincide
        float a = b1[l];
        #pragma unroll
        for (int q = 0; q < 8; ++q) {
            a = fmaf(s[q], w1[(2 * q)      * 64 + l], a);
            a = fmaf(c[q], w1[(2 * q + 1)  * 64 + l], a);
            a = fmaf(s[q], w1[(16 + 2 * q) * 64 + l], a);
            a = fmaf(c[q], w1[(17 + 2 * q) * 64 + l], a);
        }
        PE1s[0][l] = a;
    } else if (w == 1) {
        float s1v[8], c1v[8], s2v[8], c2v[8];
        pe_trig(j + 256, s1v, c1v);
        pe_trig(j,       s2v, c2v);
        float a = b1[l];
        #pragma unroll
        for (int q = 0; q < 8; ++q) {
            a = fmaf(s1v[q], w1[(2 * q)      * 64 + l], a);
            a = fmaf(c1v[q], w1[(2 * q + 1)  * 64 + l], a);
            a = fmaf(s2v[q], w1[(16 + 2 * q) * 64 + l], a);
            a = fmaf(c2v[q], w1[(17 + 2 * q) * 64 + l], a);
        }
        PE1s[1][l] = a;
    } else if (w == 2) {
        float s[8], c[8];
        pe_trig(j, s, c);
        float a = bb1[l];
        #pragma unroll
        for (int q = 0; q < 8; ++q) {
            a = fmaf(s[q], bw1[(2 * q)     * 64 + l], a);
            a = fmaf(c[q], bw1[(2 * q + 1) * 64 + l], a);
        }
        PEOs[l] = a;
    } else {
        w1cS[l] = w1[32 * 64 + l];
        w2S[l]  = w2[l];
        bwcS[l] = bw1[16 * 64 + l];
        bw2S[l] = bw2[l];
    }

    __syncthreads();

    // ---- weight MLP: W(bt, j) and W(bt, j+256), 8 hidden units per lane ----
    float a0 = 0.f, a1 = 0.f;
    #pragma unroll
    for (int kk = 0; kk < 2; ++kk) {
        const int base = s8 * 8 + kk * 4;
        const float4 p0 = *(const float4*)&PE1s[0][base];
        const float4 p1 = *(const float4*)&PE1s[1][base];
        const float4 wc = *(const float4*)&w1cS[base];
        const float4 wv = *(const float4*)&w2S[base];
        a0 += fmaxf(fmaf(xv0, wc.x, p0.x), 0.f) * wv.x;
        a0 += fmaxf(fmaf(xv0, wc.y, p0.y), 0.f) * wv.y;
        a0 += fmaxf(fmaf(xv0, wc.z, p0.z), 0.f) * wv.z;
        a0 += fmaxf(fmaf(xv0, wc.w, p0.w), 0.f) * wv.w;
        a1 += fmaxf(fmaf(xv1, wc.x, p1.x), 0.f) * wv.x;
        a1 += fmaxf(fmaf(xv1, wc.y, p1.y), 0.f) * wv.y;
        a1 += fmaxf(fmaf(xv1, wc.z, p1.z), 0.f) * wv.z;
        a1 += fmaxf(fmaf(xv1, wc.w, p1.w), 0.f) * wv.w;
    }
    #pragma unroll
    for (int mask = 1; mask <= 4; mask <<= 1) {
        a0 += __shfl_xor(a0, mask);
        a1 += __shfl_xor(a1, mask);
    }
    const float outv = (a0 + b2s_) * ses[bt] + (a1 + b2s_) * sos[bt];

    // ---- bias MLP for (bt, o=j) ----
    float bacc = 0.f;
    #pragma unroll
    for (int kk = 0; kk < 2; ++kk) {
        const int base = s8 * 8 + kk * 4;
        const float4 p  = *(const float4*)&PEOs[base];
        const float4 wc = *(const float4*)&bwcS[base];
        const float4 wv = *(const float4*)&bw2S[base];
        bacc += fmaxf(fmaf(outv, wc.x, p.x), 0.f) * wv.x;
        bacc += fmaxf(fmaf(outv, wc.y, p.y), 0.f) * wv.y;
        bacc += fmaxf(fmaf(outv, wc.z, p.z), 0.f) * wv.z;
        bacc += fmaxf(fmaf(outv, wc.w, p.w), 0.f) * wv.w;
    }
    #pragma unroll
    for (int mask = 1; mask <= 4; mask <<= 1) bacc += __shfl_xor(bacc, mask);

    if (s8 == 0) out[bt * 256 + j] = outv + bacc + bb2s_;
}

extern "C" void kernel_launch(void* const* d_in, const int* in_sizes, int n_in,
                              void* d_out, int out_size, void* d_ws, size_t ws_size,
                              hipStream_t stream) {
    const float* x   = (const float*)d_in[0];
    const float* w1  = (const float*)d_in[1];
    const float* b1  = (const float*)d_in[2];
    const float* w2  = (const float*)d_in[3];
    const float* b2  = (const float*)d_in[4];
    const float* bw1 = (const float*)d_in[5];
    const float* bb1 = (const float*)d_in[6];
    const float* bw2 = (const float*)d_in[7];
    const float* bb2 = (const float*)d_in[8];
    float* out = (float*)d_out;

    vnn_fused<<<256, 256, 0, stream>>>(x, w1, b1, w2, b2, bw1, bb1, bw2, bb2, out);
}